// Round 2
// baseline (83.190 us; speedup 1.0000x reference)
//
#include <hip/hip_runtime.h>
#include <hip/hip_bf16.h>

#define HIDDEN 128
#define NHEAD  8
#define DHEAD  16
#define KBLK   64
#define QBLK   64   // 4 waves x 16 query rows

typedef __attribute__((ext_vector_type(8))) __bf16 bf16x8;
typedef __attribute__((ext_vector_type(4))) float  f32x4;

__global__ __launch_bounds__(256, 4)
void mha_fused_kernel(const float* __restrict__ kv,
                      const float* __restrict__ q,
                      const int*   __restrict__ seq_len,
                      float* __restrict__ out,
                      int S)
{
    const int qtile = blockIdx.x;
    const int h     = blockIdx.y;
    const int b     = blockIdx.z;
    const int tid   = threadIdx.x;
    const int lane  = tid & 63;
    const int wave  = tid >> 6;
    const int L     = seq_len[b];

    // LDS row stride 72 bf16 (=144B, 9*16B): 16B-aligned b128 reads.
    // Klds: dims 0..15 = K_hi (bf16), dims 16..31 = K_lo (bf16 residual).
    __shared__ __bf16 Klds[KBLK][72];
    __shared__ __bf16 VTlds[DHEAD][72];    // [dim][key]
    __shared__ __bf16 Plds[4][16][72];     // per-wave P [q][key]

    const int g  = lane >> 4;   // quarter 0..3 (operand k-chunk)
    const int lr = lane & 15;

    // Q fragment (A operand), hi/lo packed:
    //   k-slots 0..15  = Q_hi[dim]   (lanes g=0,1)
    //   k-slots 16..31 = Q_lo[dim]   (lanes g=2,3)
    const int qbase = qtile * QBLK + wave * 16;
    bf16x8 qfrag;
    {
        const float* qp = q + ((size_t)(b * S + qbase + lr) * HIDDEN) + h * DHEAD + (g & 1) * 8;
        #pragma unroll
        for (int j = 0; j < 8; ++j) {
            float qv = qp[j] * 4.0f;          // * sqrt(d_head)
            __bf16 hi = (__bf16)qv;
            qfrag[j] = (g < 2) ? hi : (__bf16)(qv - (float)hi);
        }
    }

    f32x4 acc = {0.f, 0.f, 0.f, 0.f};
    float m[4], lsum[4];
    #pragma unroll
    for (int r = 0; r < 4; ++r) { m[r] = -1e30f; lsum[r] = 0.f; }

    const float LOG2E = 1.44269504088896340736f;

    for (int kb = 0; kb < L; kb += KBLK) {
        __syncthreads();   // protect previous tile's LDS reads before restaging

        // ---- stage K tile (hi+lo): 2 dims per thread, 32 rows per pass x2 ----
        {
            const int dp = tid & 7;         // dim pair
            const int k0 = tid >> 3;        // 0..31
            #pragma unroll
            for (int i = 0; i < 2; ++i) {
                int k = k0 + i * 32;
                const float* kp = kv + ((size_t)(b * S + kb + k) * (2 * HIDDEN)) + h * DHEAD + 2 * dp;
                float v0 = kp[0], v1 = kp[1];
                __bf16 h0 = (__bf16)v0, h1 = (__bf16)v1;
                Klds[k][2 * dp]          = h0;
                Klds[k][2 * dp + 1]      = h1;
                Klds[k][16 + 2 * dp]     = (__bf16)(v0 - (float)h0);
                Klds[k][16 + 2 * dp + 1] = (__bf16)(v1 - (float)h1);
            }
            // ---- stage V transposed ----
            const int d  = tid & 15;
            const int v0i = tid >> 4;       // 0..15
            #pragma unroll
            for (int i = 0; i < 4; ++i) {
                int k = v0i + i * 16;
                VTlds[d][k] = (__bf16)kv[((size_t)(b * S + kb + k) * (2 * HIDDEN)) + HIDDEN + h * DHEAD + d];
            }
        }
        __syncthreads();

        // ---- QK^T: 4 subtiles of 16 keys, 2 MFMAs each (hi/lo exact product) ----
        // MFMA1: B k-slots = [K_hi | K_hi]  -> qh*kh + ql*kh
        // MFMA2: B k-slots = [K_lo | K_lo]  -> qh*kl + ql*kl
        f32x4 s[4];
        #pragma unroll
        for (int sub = 0; sub < 4; ++sub) {
            const __bf16* krow = &Klds[sub * 16 + lr][0];
            bf16x8 kf1 = *(const bf16x8*)&krow[(g & 1) * 8];
            bf16x8 kf2 = *(const bf16x8*)&krow[16 + (g & 1) * 8];
            f32x4 z = {0.f, 0.f, 0.f, 0.f};
            z = __builtin_amdgcn_mfma_f32_16x16x32_bf16(qfrag, kf1, z, 0, 0, 0);
            s[sub] = __builtin_amdgcn_mfma_f32_16x16x32_bf16(qfrag, kf2, z, 0, 0, 0);
        }

        // ---- mask + row max ----
        float tmax[4];
        #pragma unroll
        for (int r = 0; r < 4; ++r) tmax[r] = -1e30f;
        #pragma unroll
        for (int sub = 0; sub < 4; ++sub) {
            const bool valid = (kb + sub * 16 + lr) < L;
            #pragma unroll
            for (int r = 0; r < 4; ++r) {
                float v = valid ? s[sub][r] : -1e30f;
                s[sub][r] = v;
                tmax[r] = fmaxf(tmax[r], v);
            }
        }
        #pragma unroll
        for (int r = 0; r < 4; ++r) {
            #pragma unroll
            for (int x = 1; x < 16; x <<= 1)
                tmax[r] = fmaxf(tmax[r], __shfl_xor(tmax[r], x));
        }

        // ---- online softmax update ----
        float alpha[4], rsum[4];
        #pragma unroll
        for (int r = 0; r < 4; ++r) {
            float mn = fmaxf(m[r], tmax[r]);
            alpha[r] = exp2f((m[r] - mn) * LOG2E);
            m[r] = mn;
            rsum[r] = 0.f;
        }
        #pragma unroll
        for (int sub = 0; sub < 4; ++sub) {
            #pragma unroll
            for (int r = 0; r < 4; ++r) {
                float p = exp2f((s[sub][r] - m[r]) * LOG2E);
                rsum[r] += p;
                Plds[wave][g * 4 + r][sub * 16 + lr] = (__bf16)p;  // P in C layout -> [q][key]
            }
        }
        #pragma unroll
        for (int r = 0; r < 4; ++r) {
            #pragma unroll
            for (int x = 1; x < 16; x <<= 1)
                rsum[r] += __shfl_xor(rsum[r], x);
            lsum[r] = lsum[r] * alpha[r] + rsum[r];
            acc[r] *= alpha[r];
        }
        __syncthreads();   // P visible (and VT already synced)

        // ---- PV: 2 MFMAs, full K=32 key contraction each ----
        #pragma unroll
        for (int half = 0; half < 2; ++half) {
            bf16x8 pf = *(const bf16x8*)&Plds[wave][lr][half * 32 + g * 8];
            bf16x8 vf = *(const bf16x8*)&VTlds[lr][half * 32 + g * 8];
            acc = __builtin_amdgcn_mfma_f32_16x16x32_bf16(pf, vf, acc, 0, 0, 0);
        }
    }

    // ---- epilogue: normalize + store ----
    #pragma unroll
    for (int r = 0; r < 4; ++r) {
        float o = acc[r] / lsum[r];
        out[((size_t)(b * S + qbase + g * 4 + r) * HIDDEN) + h * DHEAD + lr] = o;
    }
}

extern "C" void kernel_launch(void* const* d_in, const int* in_sizes, int n_in,
                              void* d_out, int out_size, void* d_ws, size_t ws_size,
                              hipStream_t stream)
{
    const float* kv      = (const float*)d_in[0];
    const float* query   = (const float*)d_in[1];
    const int*   seq_len = (const int*)d_in[2];
    float* out           = (float*)d_out;

    const int B = in_sizes[2];                        // seq_len has B elements
    const int S = in_sizes[1] / (B * HIDDEN);         // query is [B,S,HIDDEN]

    dim3 grid(S / QBLK, NHEAD, B);
    dim3 block(256);
    mha_fused_kernel<<<grid, block, 0, stream>>>(kv, query, seq_len, out, S);
}

// Round 3
// 56.725 us; speedup vs baseline: 1.4665x; 1.4665x over previous
//
#include <hip/hip_runtime.h>
#include <hip/hip_bf16.h>

#define HIDDEN 128
#define NHEAD  8
#define DHEAD  16
#define KBLK   64
#define QBLK   64   // 4 waves x 16 query rows

typedef __attribute__((ext_vector_type(8))) __bf16 bf16x8;
typedef __attribute__((ext_vector_type(4))) __bf16 bf16x4;
typedef __attribute__((ext_vector_type(4))) float  f32x4;

// ds_read_b64_tr_b16: lane supplies addr = base + lane*8; per 16-lane group the
// 128B region is redistributed so lane gets column (lane&15) of a 4x16 bf16 tile.
#define TR_READ(dst, addr, imm) \
    asm volatile("ds_read_b64_tr_b16 %0, %1 offset:" imm : "=v"(dst) : "v"(addr) : "memory")

// Storage row for key k such that tr-read elem j == MFMA operand slot g*8+j
// (per 32-key block: k = 8g+4h+j  ->  row = 16h+4g+j).
__device__ __forceinline__ int permrow(int k) {
    return (k & 3) | (((k >> 3) & 3) << 2) | (((k >> 2) & 1) << 4) | ((k >> 5) << 5);
}

__global__ __launch_bounds__(256, 4)
void mha_fused_kernel(const float* __restrict__ kv,
                      const float* __restrict__ q,
                      const int*   __restrict__ seq_len,
                      float* __restrict__ out,
                      int S)
{
    const int qtile = blockIdx.x;
    const int h     = blockIdx.y;
    const int b     = blockIdx.z;
    const int tid   = threadIdx.x;
    const int lane  = tid & 63;
    const int wave  = tid >> 6;
    const int L     = seq_len[b];

    __shared__ __bf16 Klds[KBLK][72];    // [key][dim0-15 = K_hi | dim16-31 = K_lo]
    __shared__ __bf16 Vst[KBLK][16];     // perm-rows, tr-read as PV B operand
    __shared__ __bf16 Pst[4][KBLK][16];  // per-wave P^T, perm-rows, tr-read as PV A operand

    const int g  = lane >> 4;
    const int lr = lane & 15;

    // ---- Q fragment (hoisted): slots 0-15 = Q_hi, 16-31 = Q_lo ----
    const int qbase = qtile * QBLK + wave * 16;
    bf16x8 qfrag;
    {
        const float* qp = q + ((size_t)(b * S + qbase + lr) * HIDDEN) + h * DHEAD + (g & 1) * 8;
        #pragma unroll
        for (int j = 0; j < 8; ++j) {
            float qv = qp[j] * 4.0f;          // * sqrt(d_head)
            __bf16 hi = (__bf16)qv;
            qfrag[j] = (g < 2) ? hi : (__bf16)(qv - (float)hi);
        }
    }

    // staging assignment (fixed per thread): one key, one dim-quarter
    const int skey = tid >> 2;            // 0..63
    const int qd   = tid & 3;             // dim quarter
    const int vrow = permrow(skey);
    const float* kbase = kv + ((size_t)(b * S + skey) * (2 * HIDDEN)) + h * DHEAD + 4 * qd;

    int prowP[4];
    #pragma unroll
    for (int sub = 0; sub < 4; ++sub) prowP[sub] = permrow(sub * 16 + lr);

    // LDS byte offsets for tr reads (generic shared ptr low-32 = LDS offset)
    const unsigned pbase = (unsigned)(unsigned long long)(const void*)&Pst[wave][0][0] + lane * 8;
    const unsigned vbase = (unsigned)(unsigned long long)(const void*)&Vst[0][0] + lane * 8;

    f32x4 acc = {0.f, 0.f, 0.f, 0.f};
    float m[4], lsum[4];
    #pragma unroll
    for (int r = 0; r < 4; ++r) { m[r] = -1e30f; lsum[r] = 0.f; }

    const float LOG2E = 1.44269504088896340736f;

    for (int kb = 0; kb < L; kb += KBLK) {
        __syncthreads();   // previous tile's LDS reads complete before restaging

        // ---- stage K (hi/lo split) + V, vectorized ----
        {
            const float* kp = kbase + (size_t)kb * (2 * HIDDEN);
            f32x4 kvec = *(const f32x4*)kp;
            f32x4 vvec = *(const f32x4*)(kp + HIDDEN);
            bf16x4 khv, klv, vv;
            #pragma unroll
            for (int i = 0; i < 4; ++i) {
                __bf16 hi = (__bf16)kvec[i];
                khv[i] = hi;
                klv[i] = (__bf16)(kvec[i] - (float)hi);
                vv[i]  = (__bf16)vvec[i];
            }
            *(bf16x4*)&Klds[skey][4 * qd]      = khv;
            *(bf16x4*)&Klds[skey][16 + 4 * qd] = klv;
            *(bf16x4*)&Vst[vrow][4 * qd]       = vv;
        }
        __syncthreads();

        // ---- QK^T: 4 subtiles, hi/lo exact product (2 MFMAs each) ----
        f32x4 s[4];
        #pragma unroll
        for (int sub = 0; sub < 4; ++sub) {
            const __bf16* krow = &Klds[sub * 16 + lr][0];
            bf16x8 kf1 = *(const bf16x8*)&krow[(g & 1) * 8];
            bf16x8 kf2 = *(const bf16x8*)&krow[16 + (g & 1) * 8];
            f32x4 z = {0.f, 0.f, 0.f, 0.f};
            z = __builtin_amdgcn_mfma_f32_16x16x32_bf16(qfrag, kf1, z, 0, 0, 0);
            s[sub] = __builtin_amdgcn_mfma_f32_16x16x32_bf16(qfrag, kf2, z, 0, 0, 0);
        }

        // ---- mask boundary tiles only (wave-uniform branch) ----
        if (kb + KBLK > L) {
            #pragma unroll
            for (int sub = 0; sub < 4; ++sub) {
                const bool valid = (kb + sub * 16 + lr) < L;
                #pragma unroll
                for (int r = 0; r < 4; ++r) s[sub][r] = valid ? s[sub][r] : -1e30f;
            }
        }

        // ---- row max ----
        float tmax[4];
        #pragma unroll
        for (int r = 0; r < 4; ++r)
            tmax[r] = fmaxf(fmaxf(s[0][r], s[1][r]), fmaxf(s[2][r], s[3][r]));
        #pragma unroll
        for (int r = 0; r < 4; ++r) {
            #pragma unroll
            for (int x = 1; x < 16; x <<= 1)
                tmax[r] = fmaxf(tmax[r], __shfl_xor(tmax[r], x));
        }

        // ---- online softmax update ----
        float alpha[4], rsum[4];
        #pragma unroll
        for (int r = 0; r < 4; ++r) {
            float mn = fmaxf(m[r], tmax[r]);
            alpha[r] = exp2f((m[r] - mn) * LOG2E);
            m[r] = mn;
            rsum[r] = 0.f;
        }
        #pragma unroll
        for (int sub = 0; sub < 4; ++sub) {
            bf16x4 pk;
            #pragma unroll
            for (int r = 0; r < 4; ++r) {
                float p = exp2f((s[sub][r] - m[r]) * LOG2E);
                rsum[r] += p;
                pk[r] = (__bf16)p;
            }
            *(bf16x4*)&Pst[wave][prowP[sub]][g * 4] = pk;   // P^T, packed b64
        }
        #pragma unroll
        for (int r = 0; r < 4; ++r) {
            #pragma unroll
            for (int x = 1; x < 16; x <<= 1)
                rsum[r] += __shfl_xor(rsum[r], x);
            lsum[r] = lsum[r] * alpha[r] + rsum[r];
            acc[r] *= alpha[r];
        }

        // ---- PV: tr-read P^T and V (per-wave, in-order DS pipe: no barrier) ----
        bf16x4 a0, a1, a2, a3, b0v, b1v, b2v, b3v;
        TR_READ(a0, pbase, "0");
        TR_READ(a1, pbase, "512");
        TR_READ(b0v, vbase, "0");
        TR_READ(b1v, vbase, "512");
        TR_READ(a2, pbase, "1024");
        TR_READ(a3, pbase, "1536");
        TR_READ(b2v, vbase, "1024");
        TR_READ(b3v, vbase, "1536");
        asm volatile("s_waitcnt lgkmcnt(0)" ::: "memory");
        __builtin_amdgcn_sched_barrier(0);
        bf16x8 pa0, vb0, pa1, vb1;
        #pragma unroll
        for (int i = 0; i < 4; ++i) {
            pa0[i] = a0[i];  pa0[i + 4] = a1[i];
            vb0[i] = b0v[i]; vb0[i + 4] = b1v[i];
            pa1[i] = a2[i];  pa1[i + 4] = a3[i];
            vb1[i] = b2v[i]; vb1[i + 4] = b3v[i];
        }
        acc = __builtin_amdgcn_mfma_f32_16x16x32_bf16(pa0, vb0, acc, 0, 0, 0);
        acc = __builtin_amdgcn_mfma_f32_16x16x32_bf16(pa1, vb1, acc, 0, 0, 0);
    }

    // ---- epilogue: normalize + store ----
    #pragma unroll
    for (int r = 0; r < 4; ++r) {
        float o = acc[r] / lsum[r];
        out[((size_t)(b * S + qbase + g * 4 + r) * HIDDEN) + h * DHEAD + lr] = o;
    }
}

extern "C" void kernel_launch(void* const* d_in, const int* in_sizes, int n_in,
                              void* d_out, int out_size, void* d_ws, size_t ws_size,
                              hipStream_t stream)
{
    const float* kv      = (const float*)d_in[0];
    const float* query   = (const float*)d_in[1];
    const int*   seq_len = (const int*)d_in[2];
    float* out           = (float*)d_out;

    const int B = in_sizes[2];
    const int S = in_sizes[1] / (B * HIDDEN);

    dim3 grid(S / QBLK, NHEAD, B);
    dim3 block(256);
    mha_fused_kernel<<<grid, block, 0, stream>>>(kv, query, seq_len, out, S);
}

// Round 4
// 46.427 us; speedup vs baseline: 1.7918x; 1.2218x over previous
//
#include <hip/hip_runtime.h>
#include <hip/hip_bf16.h>

#define HIDDEN 128
#define NHEAD  8
#define DHEAD  16
#define KBLK   64
#define QBLK   64     // 4 waves x 16 query rows
#define CHUNK  512    // split-K chunk (multiple of KBLK)

typedef __attribute__((ext_vector_type(8))) __bf16 bf16x8;
typedef __attribute__((ext_vector_type(4))) __bf16 bf16x4;
typedef __attribute__((ext_vector_type(4))) float  f32x4;
typedef __attribute__((ext_vector_type(2))) float  f32x2;

#define LOG2E 1.44269504088896340736f

// ds_read_b64_tr_b16: per 16-lane group redistributes a 128B region so lane
// gets column (lane&15) of a 4x16 bf16 tile.
#define TR_READ(dst, addr, imm) \
    asm volatile("ds_read_b64_tr_b16 %0, %1 offset:" imm : "=v"(dst) : "v"(addr) : "memory")

// Storage row for key k such that tr-read elem j == MFMA operand slot g*8+j.
__device__ __forceinline__ int permrow(int k) {
    return (k & 3) | (((k >> 3) & 3) << 2) | (((k >> 2) & 1) << 4) | ((k >> 5) << 5);
}

template<bool SPLIT>
__global__ __launch_bounds__(256, 8)
void mha_fwd(const float* __restrict__ kv,
             const float* __restrict__ q,
             const int*   __restrict__ seq_len,
             float* __restrict__ out,    // !SPLIT only
             float* __restrict__ pbuf,   // [b][c][q][h][16]
             float* __restrict__ mlbuf,  // [b][c][q][h][2]
             int S, int nc)
{
    const int qtile = blockIdx.x;
    const int h     = blockIdx.y;
    int b, c0;
    if (SPLIT) { b = blockIdx.z / nc; c0 = blockIdx.z % nc; }
    else       { b = blockIdx.z;      c0 = 0; }
    const int L = seq_len[b];
    const int kstart = SPLIT ? c0 * CHUNK : 0;
    if (SPLIT && kstart >= L) return;              // uniform exit, before any barrier
    const int kend = SPLIT ? min(L, kstart + CHUNK) : L;

    const int tid  = threadIdx.x;
    const int lane = tid & 63;
    const int wave = tid >> 6;
    const int g    = lane >> 4;
    const int lr   = lane & 15;

    // LDS (16 KB total): strides chosen for uniform bank phases on b128 reads.
    __shared__ __bf16 Klds[KBLK][40];      // [key][dims 0-15 = K_hi | 16-31 = K_lo]
    __shared__ __bf16 Vst[KBLK][16];       // perm rows, tr-read as PV A(V^T) operand
    __shared__ __bf16 Pst[4][16][72];      // per-wave P [q][key]

    // ---- Q fragment (B operand of swapped QK): slots 0-15 = Q_hi, 16-31 = Q_lo ----
    const int qbase = qtile * QBLK + wave * 16;
    bf16x8 qfrag;
    {
        const float* qp = q + ((size_t)(b * S + qbase + lr) * HIDDEN) + h * DHEAD + (g & 1) * 8;
        #pragma unroll
        for (int j = 0; j < 8; ++j) {
            float qv = qp[j] * 4.0f;               // * sqrt(d_head)
            __bf16 hi = (__bf16)qv;
            qfrag[j] = (g < 2) ? hi : (__bf16)(qv - (float)hi);
        }
    }

    // staging assignment: one key, one dim-quarter per thread
    const int skey = tid >> 2;
    const int qd   = tid & 3;
    const int vrow = permrow(skey);
    const float* kbase = kv + ((size_t)(b * S + skey) * (2 * HIDDEN)) + h * DHEAD + 4 * qd;

    const unsigned vbase = (unsigned)(unsigned long long)(const void*)&Vst[0][0] + lane * 8;

    f32x4 acc = {0.f, 0.f, 0.f, 0.f};     // acc[r] = O^T[d = g*4+r][q = lr]
    float m = -1e30f, lsum = 0.f;

    for (int kb = kstart; kb < kend; kb += KBLK) {
        __syncthreads();   // previous tile's LDS reads complete before restaging

        // ---- stage K (hi/lo split) + V ----
        {
            const float* kp = kbase + (size_t)kb * (2 * HIDDEN);
            f32x4 kvec = *(const f32x4*)kp;
            f32x4 vvec = *(const f32x4*)(kp + HIDDEN);
            bf16x4 khv, klv, vv;
            #pragma unroll
            for (int i = 0; i < 4; ++i) {
                __bf16 hi = (__bf16)kvec[i];
                khv[i] = hi;
                klv[i] = (__bf16)(kvec[i] - (float)hi);
                vv[i]  = (__bf16)vvec[i];
            }
            *(bf16x4*)&Klds[skey][4 * qd]      = khv;
            *(bf16x4*)&Klds[skey][16 + 4 * qd] = klv;
            *(bf16x4*)&Vst[vrow][4 * qd]       = vv;
        }
        __syncthreads();

        // ---- QK^T swapped: S^T = K * Q^T; s[sub][r] = S[q=lr][key=sub*16+g*4+r] ----
        // MFMA1: A slots = [K_hi | K_hi], B = [Q_hi | Q_lo] -> kh*(qh+ql)
        // MFMA2: A slots = [K_lo | K_lo]                    -> kl*(qh+ql)
        f32x4 s[4];
        #pragma unroll
        for (int sub = 0; sub < 4; ++sub) {
            const __bf16* krow = &Klds[sub * 16 + lr][0];
            bf16x8 kf1 = *(const bf16x8*)&krow[(g & 1) * 8];
            bf16x8 kf2 = *(const bf16x8*)&krow[16 + (g & 1) * 8];
            f32x4 z = {0.f, 0.f, 0.f, 0.f};
            z = __builtin_amdgcn_mfma_f32_16x16x32_bf16(kf1, qfrag, z, 0, 0, 0);
            s[sub] = __builtin_amdgcn_mfma_f32_16x16x32_bf16(kf2, qfrag, z, 0, 0, 0);
        }

        // ---- mask boundary tile only (in-lane key index) ----
        if (kb + KBLK > kend) {
            #pragma unroll
            for (int sub = 0; sub < 4; ++sub)
                #pragma unroll
                for (int r = 0; r < 4; ++r)
                    if (kb + sub * 16 + g * 4 + r >= kend) s[sub][r] = -1e30f;
        }

        // ---- row max: 15 in-lane + 2 shfl ----
        float t0 = fmaxf(fmaxf(s[0][0], s[0][1]), fmaxf(s[0][2], s[0][3]));
        float t1 = fmaxf(fmaxf(s[1][0], s[1][1]), fmaxf(s[1][2], s[1][3]));
        float t2 = fmaxf(fmaxf(s[2][0], s[2][1]), fmaxf(s[2][2], s[2][3]));
        float t3 = fmaxf(fmaxf(s[3][0], s[3][1]), fmaxf(s[3][2], s[3][3]));
        float tmax = fmaxf(fmaxf(t0, t1), fmaxf(t2, t3));
        tmax = fmaxf(tmax, __shfl_xor(tmax, 16));
        tmax = fmaxf(tmax, __shfl_xor(tmax, 32));

        // ---- online softmax (per-lane scalars, q = lr) ----
        const float mn = fmaxf(m, tmax);
        const float alpha = exp2f((m - mn) * LOG2E);
        m = mn;
        float rsum = 0.f;
        #pragma unroll
        for (int sub = 0; sub < 4; ++sub) {
            bf16x4 pk;
            #pragma unroll
            for (int r = 0; r < 4; ++r) {
                float p = exp2f((s[sub][r] - mn) * LOG2E);
                rsum += p;
                pk[r] = (__bf16)p;
            }
            *(bf16x4*)&Pst[wave][lr][sub * 16 + g * 4] = pk;
        }
        rsum += __shfl_xor(rsum, 16);
        rsum += __shfl_xor(rsum, 32);
        lsum = lsum * alpha + rsum;
        acc *= alpha;

        // ---- PV swapped: O^T = V^T * P^T (per-wave DS, in-order, no barrier) ----
        bf16x4 b0v, b1v, b2v, b3v;
        TR_READ(b0v, vbase, "0");
        TR_READ(b1v, vbase, "512");
        TR_READ(b2v, vbase, "1024");
        TR_READ(b3v, vbase, "1536");
        bf16x8 pa0 = *(const bf16x8*)&Pst[wave][lr][g * 8];        // keys 0-31
        bf16x8 pa1 = *(const bf16x8*)&Pst[wave][lr][32 + g * 8];   // keys 32-63
        asm volatile("s_waitcnt lgkmcnt(0)" ::: "memory");
        __builtin_amdgcn_sched_barrier(0);
        bf16x8 vb0, vb1;
        #pragma unroll
        for (int i = 0; i < 4; ++i) {
            vb0[i] = b0v[i]; vb0[i + 4] = b1v[i];
            vb1[i] = b2v[i]; vb1[i + 4] = b3v[i];
        }
        acc = __builtin_amdgcn_mfma_f32_16x16x32_bf16(vb0, pa0, acc, 0, 0, 0);
        acc = __builtin_amdgcn_mfma_f32_16x16x32_bf16(vb1, pa1, acc, 0, 0, 0);
    }

    // ---- epilogue ----
    const int qglob = qbase + lr;
    if (SPLIT) {
        const size_t row = (((size_t)b * nc + c0) * S + qglob) * NHEAD + h;
        *(f32x4*)&pbuf[row * DHEAD + g * 4] = acc;          // unnormalized, scaled by e^-m
        if (g == 0) { f32x2 ml = {m, lsum}; *(f32x2*)&mlbuf[row * 2] = ml; }
    } else {
        const float inv = 1.0f / lsum;
        *(f32x4*)&out[((size_t)b * S + qglob) * HIDDEN + h * DHEAD + g * 4] = acc * inv;
    }
}

__global__ __launch_bounds__(256)
void mha_merge(const float* __restrict__ pbuf, const float* __restrict__ mlbuf,
               const int* __restrict__ seq_len, float* __restrict__ out, int S, int nc)
{
    const int t = blockIdx.x * 256 + threadIdx.x;   // (b, q, h) with h fastest
    const int h = t & (NHEAD - 1);
    const int rest = t >> 3;
    const int qg = rest % S;
    const int b  = rest / S;
    const int L  = seq_len[b];
    const int nch = (L + CHUNK - 1) / CHUNK;

    const size_t cstr = (size_t)S * NHEAD;
    const size_t row0 = ((size_t)b * nc) * cstr + (size_t)qg * NHEAD + h;

    float mv[8], lv[8];
    float M = -1e30f;
    for (int c = 0; c < nch; ++c) {
        f32x2 ml = *(const f32x2*)&mlbuf[(row0 + c * cstr) * 2];
        mv[c] = ml[0]; lv[c] = ml[1];
        M = fmaxf(M, ml[0]);
    }
    float den = 0.f;
    f32x4 o0 = {0,0,0,0}, o1 = o0, o2 = o0, o3 = o0;
    for (int c = 0; c < nch; ++c) {
        float w = exp2f((mv[c] - M) * LOG2E);
        den += w * lv[c];
        const float* pp = &pbuf[(row0 + c * cstr) * DHEAD];
        o0 += w * *(const f32x4*)&pp[0];
        o1 += w * *(const f32x4*)&pp[4];
        o2 += w * *(const f32x4*)&pp[8];
        o3 += w * *(const f32x4*)&pp[12];
    }
    const float inv = 1.0f / den;
    float* op = &out[((size_t)b * S + qg) * HIDDEN + h * DHEAD];
    *(f32x4*)&op[0]  = o0 * inv;
    *(f32x4*)&op[4]  = o1 * inv;
    *(f32x4*)&op[8]  = o2 * inv;
    *(f32x4*)&op[12] = o3 * inv;
}

extern "C" void kernel_launch(void* const* d_in, const int* in_sizes, int n_in,
                              void* d_out, int out_size, void* d_ws, size_t ws_size,
                              hipStream_t stream)
{
    const float* kv      = (const float*)d_in[0];
    const float* query   = (const float*)d_in[1];
    const int*   seq_len = (const int*)d_in[2];
    float* out           = (float*)d_out;

    const int B = in_sizes[2];
    const int S = in_sizes[1] / (B * HIDDEN);
    const int nc = (S + CHUNK - 1) / CHUNK;

    const size_t pbytes  = (size_t)B * nc * S * NHEAD * DHEAD * sizeof(float);
    const size_t mlbytes = (size_t)B * nc * S * NHEAD * 2 * sizeof(float);

    if (ws_size >= pbytes + mlbytes && nc <= 8) {
        float* pbuf  = (float*)d_ws;
        float* mlbuf = (float*)((char*)d_ws + pbytes);
        dim3 grid(S / QBLK, NHEAD, B * nc);
        mha_fwd<true><<<grid, dim3(256), 0, stream>>>(kv, query, seq_len, nullptr, pbuf, mlbuf, S, nc);
        const int nrows = B * S * NHEAD;
        mha_merge<<<dim3((nrows + 255) / 256), dim3(256), 0, stream>>>(pbuf, mlbuf, seq_len, out, S, nc);
    } else {
        dim3 grid(S / QBLK, NHEAD, B);
        mha_fwd<false><<<grid, dim3(256), 0, stream>>>(kv, query, seq_len, out, nullptr, nullptr, S, 1);
    }
}